// Round 16
// baseline (1687.185 us; speedup 1.0000x reference)
//
#include <hip/hip_runtime.h>
#include <stdint.h>

typedef _Float16 f16;
typedef _Float16 f16x8 __attribute__((ext_vector_type(8)));
typedef float f32x4 __attribute__((ext_vector_type(4)));

#define TT 256
#define BB 256
#define II 128
#define HH 512
#define G4 2048
#define NGRP 8
static constexpr size_t BH = (size_t)BB * HH;
// flag line: 256B per (grp,tick) = 128 u16 slots (32 slices x 4 waves)
static constexpr size_t FLG_LINE_U16 = 128;
static constexpr size_t FLG_ARR_U16 = (size_t)NGRP * (TT + 1) * FLG_LINE_U16;

// ---------------- coherence helpers (sc1/agent — proven protocol) ----------------
__device__ __forceinline__ uint64_t ld_agent_u64(const uint64_t* p) {
  return __hip_atomic_load(p, __ATOMIC_RELAXED, __HIP_MEMORY_SCOPE_AGENT);
}
__device__ __forceinline__ void st_agent_u32(uint32_t* p, uint32_t v) {
  __hip_atomic_store(p, v, __ATOMIC_RELAXED, __HIP_MEMORY_SCOPE_AGENT);
}
__device__ __forceinline__ void st_agent_u16(uint16_t* p, uint16_t v) {
  __hip_atomic_store(p, v, __ATOMIC_RELAXED, __HIP_MEMORY_SCOPE_AGENT);
}
// 8x dwordx4 sc1 loads of one 32KB h-tile row-part (stride 128B), full drain.
__device__ __forceinline__ void ld8t_sc1(const void* b, uint4 v[8]) {
  asm volatile(
      "global_load_dwordx4 %0, %8, off sc1\n\t"
      "global_load_dwordx4 %1, %8, off offset:128 sc1\n\t"
      "global_load_dwordx4 %2, %8, off offset:256 sc1\n\t"
      "global_load_dwordx4 %3, %8, off offset:384 sc1\n\t"
      "global_load_dwordx4 %4, %8, off offset:512 sc1\n\t"
      "global_load_dwordx4 %5, %8, off offset:640 sc1\n\t"
      "global_load_dwordx4 %6, %8, off offset:768 sc1\n\t"
      "global_load_dwordx4 %7, %8, off offset:896 sc1\n\t"
      "s_waitcnt vmcnt(0)"
      : "=&v"(v[0]), "=&v"(v[1]), "=&v"(v[2]), "=&v"(v[3]),
        "=&v"(v[4]), "=&v"(v[5]), "=&v"(v[6]), "=&v"(v[7])
      : "v"(b)
      : "memory");
}

__device__ __forceinline__ float fsig(float x) {
  x = fminf(fmaxf(x, -30.f), 30.f);
  float e = __builtin_amdgcn_exp2f(-1.44269504f * x);
  return __builtin_amdgcn_rcpf(1.f + e);
}
__device__ __forceinline__ float ftanh(float x) {
  x = fminf(fmaxf(x, -15.f), 15.f);
  float e = __builtin_amdgcn_exp2f(-2.88539008f * x);  // exp(-2x)
  return (1.f - e) * __builtin_amdgcn_rcpf(1.f + e);
}

// swizzled LDS fragment reads (granule = 16B, XOR with row&7)
__device__ __forceinline__ f16x8 ldfragh(const f16* S, int row, int gi) {
  return *(const f16x8*)(S + row * 512 + ((gi ^ (row & 7)) * 8));
}
__device__ __forceinline__ f16x8 ldfragx(const f16* S, int row, int gi) {
  return *(const f16x8*)(S + row * 128 + ((gi ^ (row & 7)) * 8));
}

__global__ void k_diag(float* out, float val) { out[0] = val; }

// ---------------- x transpose/convert: [B][T][I] f32 -> [T][B][I] f16 ----------------
__global__ __launch_bounds__(256) void k_conv_x(const float* __restrict__ x,
                                                f16* __restrict__ xt) {
  int idx = blockIdx.x * 256 + threadIdx.x;  // unit = 8 floats
  int row = idx >> 4;                        // row = t*B + b
  int ii = (idx & 15) * 8;
  int t = row >> 8, b = row & 255;
  const float4* xs = (const float4*)(x + ((size_t)b * TT + t) * II + ii);
  float4 v0 = xs[0];
  float4 v1 = xs[1];
  f16x8 h;
  h[0] = (f16)v0.x; h[1] = (f16)v0.y; h[2] = (f16)v0.z; h[3] = (f16)v0.w;
  h[4] = (f16)v1.x; h[5] = (f16)v1.y; h[6] = (f16)v1.z; h[7] = (f16)v1.w;
  *(f16x8*)(xt + (size_t)row * II + ii) = h;
}

// ---------------- convert weights to f16, sum biases ----------------
__global__ __launch_bounds__(256) void k_conv_w(
    const float* __restrict__ wih0, const float* __restrict__ whh0,
    const float* __restrict__ wih1, const float* __restrict__ whh1,
    const float* __restrict__ bih0, const float* __restrict__ bhh0,
    const float* __restrict__ bih1, const float* __restrict__ bhh1,
    f16* owih0, f16* owhh0, f16* owih1, f16* owhh1, float* ob0, float* ob1) {
  int i = blockIdx.x * 256 + threadIdx.x;
  if (i < G4 * II) owih0[i] = (f16)wih0[i];
  if (i < G4 * HH) {
    owhh0[i] = (f16)whh0[i];
    owih1[i] = (f16)wih1[i];
    owhh1[i] = (f16)whh1[i];
  }
  if (i < G4) {
    ob0[i] = bih0[i] + bhh0[i];
    ob1[i] = bih1[i] + bhh1[i];
  }
}

// ---------------- decoupled 2-layer wavefront LSTM ----------------
// 512 blocks x 256 threads, 2 blocks/CU. Even blocks = L0 chain (h1),
// odd = L1 chain (h2); CU hardware scheduler overlaps the two chains'
// waves (m114 mechanism) instead of intra-block software pipelining.
// Each chain's independent work sits BEFORE its dependent poll, so it is
// absorbed into the wait: L0 pre-poll = x-stage; L1 pre-poll = h1-stage +
// 32 wih1-MFMAs. h1 ring depth 4 + reverse throttle flagL1[u-4] keeps
// overwrites safe with L1 lag in [1,4] ticks. Deadlock-free (acyclic with
// slack); guards as safety net.
__global__ __launch_bounds__(256, 2) void k_fused(
    const f16* __restrict__ xt,
    const f16* __restrict__ Wih0, const f16* __restrict__ Whh0,
    const f16* __restrict__ Wih1, const f16* __restrict__ Whh1,
    const float* __restrict__ b0, const float* __restrict__ b1,
    f16* __restrict__ h1r, f16* __restrict__ h2r,
    uint16_t* __restrict__ flag1, uint16_t* __restrict__ flagL1) {
  __shared__ __align__(16) f16 h1s[32 * 512];   // 32KB, swizzled
  __shared__ __align__(16) f16 h2s[32 * 512];   // 32KB (L0 aliases 8KB as xs)
  __shared__ __align__(16) float gs[64][36];    // 9KB gate preacts

  int tid = threadIdx.x;
  int l64 = tid & 63;
  int wid = tid >> 6;        // wave = gate chunk (i,f,g,o)
  int lm = l64 & 15, ls = l64 >> 4;
  int bx = blockIdx.x;
  int role = bx & 1;         // 0 = L0 chain, 1 = L1 chain
  int id = bx >> 1;          // 0..255
  int grp = id & 7;
  int slice = id >> 3;       // 0..31
  int col0 = slice * 16;
  int row0 = grp * 32;
  int sr = tid >> 3;         // staging row 0..31
  int gx = tid & 7;          // staging granule
  int er = tid >> 3;         // ew row 0..31
  int eq = tid & 7;          // ew col-pair
  const uint64_t kT = 0x0001000100010001ULL;

  if (role == 0) {
    // =================== L0 chain: h1_u = LSTM0(x_u, h1_{u-1}) ===================
    int wrow = wid * 512 + col0 + lm;
    f16x8 wi[4], wh[16];
#pragma unroll
    for (int kk = 0; kk < 4; ++kk)
      wi[kk] = *(const f16x8*)(Wih0 + (size_t)wrow * II + kk * 32 + ls * 8);
#pragma unroll
    for (int kk = 0; kk < 16; ++kk)
      wh[kk] = *(const f16x8*)(Whh0 + (size_t)wrow * HH + kk * 32 + ls * 8);
    float bias[4][2];
#pragma unroll
    for (int g = 0; g < 4; ++g)
#pragma unroll
      for (int j = 0; j < 2; ++j) bias[g][j] = b0[g * HH + col0 + eq * 2 + j];
    float c1[2] = {0.f, 0.f};
    f16* xs = (f16*)h2s;  // alias: L0 never uses h2s

#pragma unroll 1
    for (int u = 0; u < TT; ++u) {
      // pre-poll: stage x_u (absorbed into the wait)
      {
        const uint4* src = (const uint4*)(xt + ((size_t)u * BB + row0 + sr) * II);
        uint4 xv0 = src[gx];
        uint4 xv1 = src[gx + 8];
        uint4* dx = (uint4*)xs;
        dx[sr * 16 + (gx ^ (sr & 7))] = xv0;
        dx[sr * 16 + ((gx + 8) ^ (sr & 7))] = xv1;
      }
      if (u > 0) {
        // poll: h1_{u-1} ready (L0 peers) AND L1 progress >= u-4 (ring throttle)
        const uint64_t* f1 =
            (const uint64_t*)(flag1 + ((size_t)grp * (TT + 1) + (u - 1)) * FLG_LINE_U16);
        const uint64_t* f2 =
            (const uint64_t*)(flagL1 +
                              ((size_t)grp * (TT + 1) + (u >= 4 ? u - 4 : 0)) * FLG_LINE_U16);
        int guard = 0;
        for (;;) {
          uint64_t v1 = ld_agent_u64(f1 + (l64 & 31));
          bool ok = (v1 == kT);
          if (u >= 4) {
            uint64_t v2 = ld_agent_u64(f2 + (l64 & 31));
            ok = ok && (v2 == kT);
          }
          if (__all(ok)) break;
          if (++guard > 800000) break;  // deadlock safety net
          __builtin_amdgcn_s_sleep(1);
        }
        asm volatile("" ::: "memory");
        // stage h1_{u-1} (slot (u-1)&3)
        const f16* base =
            h1r + (size_t)((u - 1) & 3) * BH + (size_t)(row0 + sr) * HH + gx * 8;
        uint4 hv[8];
        ld8t_sc1(base, hv);
        uint4* d1 = (uint4*)h1s;
#pragma unroll
        for (int q = 0; q < 8; ++q) {
          int gi = gx + q * 8;
          d1[sr * 64 + (gi ^ (sr & 7))] = hv[q];
        }
      }
      __syncthreads();  // barrier A: xs/h1s visible; orders prev ew gs reads

      f32x4 a0 = {0.f, 0.f, 0.f, 0.f}, a1 = {0.f, 0.f, 0.f, 0.f};
#pragma unroll
      for (int kk = 0; kk < 4; ++kk) {
        f16x8 xA = ldfragx(xs, lm, kk * 4 + ls);
        f16x8 xB = ldfragx(xs, 16 + lm, kk * 4 + ls);
        a0 = __builtin_amdgcn_mfma_f32_16x16x32_f16(xA, wi[kk], a0, 0, 0, 0);
        a1 = __builtin_amdgcn_mfma_f32_16x16x32_f16(xB, wi[kk], a1, 0, 0, 0);
      }
      if (u > 0) {
#pragma unroll
        for (int kk = 0; kk < 16; ++kk) {
          f16x8 hA = ldfragh(h1s, lm, kk * 4 + ls);
          f16x8 hB = ldfragh(h1s, 16 + lm, kk * 4 + ls);
          a0 = __builtin_amdgcn_mfma_f32_16x16x32_f16(hA, wh[kk], a0, 0, 0, 0);
          a1 = __builtin_amdgcn_mfma_f32_16x16x32_f16(hB, wh[kk], a1, 0, 0, 0);
        }
      }
      *(f32x4*)&gs[wid * 16 + lm][ls * 4] = a0;
      *(f32x4*)&gs[wid * 16 + lm][16 + ls * 4] = a1;
      __syncthreads();  // barrier B: gs visible; all LDS reads done

      // ew: 2 cells (row er, cols eq*2..+1)
      union { uint32_t v; unsigned short us[2]; } pk;
#pragma unroll
      for (int j = 0; j < 2; ++j) {
        int cl = eq * 2 + j;
        float pi = gs[0 * 16 + cl][er] + bias[0][j];
        float pf = gs[1 * 16 + cl][er] + bias[1][j];
        float pg = gs[2 * 16 + cl][er] + bias[2][j];
        float po = gs[3 * 16 + cl][er] + bias[3][j];
        float ig = fsig(pi), fg = fsig(pf), gg = ftanh(pg), og = fsig(po);
        c1[j] = fg * c1[j] + ig * gg;
        pk.us[j] = __builtin_bit_cast(unsigned short, (f16)(og * ftanh(c1[j])));
      }
      st_agent_u32((uint32_t*)(h1r + (size_t)(u & 3) * BH +
                               (size_t)(row0 + er) * HH + col0 + eq * 2),
                   pk.v);
      asm volatile("s_waitcnt vmcnt(0)" ::: "memory");  // wave-local drain
      if (l64 == 0)
        st_agent_u16(flag1 + ((size_t)grp * (TT + 1) + u) * FLG_LINE_U16 +
                         slice * 4 + wid,
                     1u);
    }
  } else {
    // =================== L1 chain: h2_v = LSTM1(h1_v, h2_{v-1}) ===================
    int wrow = wid * 512 + col0 + lm;
    f16x8 wi[16], wh[16];
#pragma unroll
    for (int kk = 0; kk < 16; ++kk) {
      wi[kk] = *(const f16x8*)(Wih1 + (size_t)wrow * HH + kk * 32 + ls * 8);
      wh[kk] = *(const f16x8*)(Whh1 + (size_t)wrow * HH + kk * 32 + ls * 8);
    }
    float bias[4][2];
#pragma unroll
    for (int g = 0; g < 4; ++g)
#pragma unroll
      for (int j = 0; j < 2; ++j) bias[g][j] = b1[g * HH + col0 + eq * 2 + j];
    float c2[2] = {0.f, 0.f};

#pragma unroll 1
    for (int v = 0; v < TT; ++v) {
      // poll flag1[v] (h1_v ready; L0 runs ahead -> normally satisfied)
      {
        const uint64_t* f1 =
            (const uint64_t*)(flag1 + ((size_t)grp * (TT + 1) + v) * FLG_LINE_U16);
        int guard = 0;
        for (;;) {
          uint64_t v1 = ld_agent_u64(f1 + (l64 & 31));
          if (__all(v1 == kT)) break;
          if (++guard > 800000) break;
          __builtin_amdgcn_s_sleep(1);
        }
        asm volatile("" ::: "memory");
      }
      // stage h1_v (slot v&3) — pre-(h2)-poll work
      {
        const f16* base =
            h1r + (size_t)(v & 3) * BH + (size_t)(row0 + sr) * HH + gx * 8;
        uint4 hv[8];
        ld8t_sc1(base, hv);
        uint4* d1 = (uint4*)h1s;
#pragma unroll
        for (int q = 0; q < 8; ++q) {
          int gi = gx + q * 8;
          d1[sr * 64 + (gi ^ (sr & 7))] = hv[q];
        }
      }
      __syncthreads();  // barrier A: h1s visible; orders prev ew gs reads

      // a1i: h1_v · Wih1 (independent of h2 -> before the h2 poll)
      f32x4 a0 = {0.f, 0.f, 0.f, 0.f}, a1 = {0.f, 0.f, 0.f, 0.f};
#pragma unroll
      for (int kk = 0; kk < 16; ++kk) {
        f16x8 hA = ldfragh(h1s, lm, kk * 4 + ls);
        f16x8 hB = ldfragh(h1s, 16 + lm, kk * 4 + ls);
        a0 = __builtin_amdgcn_mfma_f32_16x16x32_f16(hA, wi[kk], a0, 0, 0, 0);
        a1 = __builtin_amdgcn_mfma_f32_16x16x32_f16(hB, wi[kk], a1, 0, 0, 0);
      }
      if (v > 0) {
        // poll flagL1[v-1] (h2_{v-1} from L1 peers) — the L1 self-cycle edge
        const uint64_t* f2 =
            (const uint64_t*)(flagL1 + ((size_t)grp * (TT + 1) + (v - 1)) * FLG_LINE_U16);
        int guard = 0;
        for (;;) {
          uint64_t v2 = ld_agent_u64(f2 + (l64 & 31));
          if (__all(v2 == kT)) break;
          if (++guard > 800000) break;
          __builtin_amdgcn_s_sleep(1);
        }
        asm volatile("" ::: "memory");
        // stage h2_{v-1} (slot (v-1)&1)
        const f16* base =
            h2r + (size_t)((v - 1) & 1) * BH + (size_t)(row0 + sr) * HH + gx * 8;
        uint4 hv[8];
        ld8t_sc1(base, hv);
        uint4* d2 = (uint4*)h2s;
#pragma unroll
        for (int q = 0; q < 8; ++q) {
          int gi = gx + q * 8;
          d2[sr * 64 + (gi ^ (sr & 7))] = hv[q];
        }
      }
      __syncthreads();  // barrier B: h2s visible

      if (v > 0) {
#pragma unroll
        for (int kk = 0; kk < 16; ++kk) {
          f16x8 kA = ldfragh(h2s, lm, kk * 4 + ls);
          f16x8 kB = ldfragh(h2s, 16 + lm, kk * 4 + ls);
          a0 = __builtin_amdgcn_mfma_f32_16x16x32_f16(kA, wh[kk], a0, 0, 0, 0);
          a1 = __builtin_amdgcn_mfma_f32_16x16x32_f16(kB, wh[kk], a1, 0, 0, 0);
        }
      }
      *(f32x4*)&gs[wid * 16 + lm][ls * 4] = a0;
      *(f32x4*)&gs[wid * 16 + lm][16 + ls * 4] = a1;
      __syncthreads();  // barrier C: gs visible; all LDS reads done

      union { uint32_t v; unsigned short us[2]; } pk;
#pragma unroll
      for (int j = 0; j < 2; ++j) {
        int cl = eq * 2 + j;
        float pi = gs[0 * 16 + cl][er] + bias[0][j];
        float pf = gs[1 * 16 + cl][er] + bias[1][j];
        float pg = gs[2 * 16 + cl][er] + bias[2][j];
        float po = gs[3 * 16 + cl][er] + bias[3][j];
        float ig = fsig(pi), fg = fsig(pf), gg = ftanh(pg), og = fsig(po);
        c2[j] = fg * c2[j] + ig * gg;
        pk.us[j] = __builtin_bit_cast(unsigned short, (f16)(og * ftanh(c2[j])));
      }
      st_agent_u32((uint32_t*)(h2r + (size_t)(v & 1) * BH +
                               (size_t)(row0 + er) * HH + col0 + eq * 2),
                   pk.v);
      asm volatile("s_waitcnt vmcnt(0)" ::: "memory");  // wave-local drain
      if (l64 == 0)
        st_agent_u16(flagL1 + ((size_t)grp * (TT + 1) + v) * FLG_LINE_U16 +
                         slice * 4 + wid,
                     1u);
    }
  }
}

// ---------------- FC head: out[b] = h2_last[b][:] . fcw + fcb ----------------
__global__ __launch_bounds__(64) void k_fc(const f16* __restrict__ h2,
                                           const float* __restrict__ fcw,
                                           const float* __restrict__ fcb,
                                           float* __restrict__ out) {
  int b = blockIdx.x;
  int l = threadIdx.x;
  f16x8 hv = *(const f16x8*)(h2 + (size_t)b * HH + l * 8);
  float4 w0 = ((const float4*)fcw)[l * 2];
  float4 w1 = ((const float4*)fcw)[l * 2 + 1];
  float s = (float)hv[0] * w0.x + (float)hv[1] * w0.y + (float)hv[2] * w0.z +
            (float)hv[3] * w0.w + (float)hv[4] * w1.x + (float)hv[5] * w1.y +
            (float)hv[6] * w1.z + (float)hv[7] * w1.w;
#pragma unroll
  for (int off = 32; off > 0; off >>= 1) s += __shfl_down(s, off);
  if (l == 0) out[b] = s + fcb[0];
}

// ---------------- launch ----------------
extern "C" void kernel_launch(void* const* d_in, const int* in_sizes, int n_in,
                              void* d_out, int out_size, void* d_ws, size_t ws_size,
                              hipStream_t stream) {
  (void)in_sizes; (void)n_in; (void)out_size;

  const float* x    = (const float*)d_in[0];
  const float* wih0 = (const float*)d_in[1];
  const float* whh0 = (const float*)d_in[2];
  const float* bih0 = (const float*)d_in[3];
  const float* bhh0 = (const float*)d_in[4];
  const float* wih1 = (const float*)d_in[5];
  const float* whh1 = (const float*)d_in[6];
  const float* bih1 = (const float*)d_in[7];
  const float* bhh1 = (const float*)d_in[8];
  const float* fcw  = (const float*)d_in[9];
  const float* fcb  = (const float*)d_in[10];

  const size_t SZ_XT    = (size_t)TT * BB * II * 2;   // 16.8 MB
  const size_t SZ_WIH0  = (size_t)G4 * II * 2;
  const size_t SZ_W     = (size_t)G4 * HH * 2;
  const size_t SZ_B     = (size_t)G4 * 4;
  const size_t SZ_RING1 = (size_t)4 * BH * 2;         // h1 ring depth 4
  const size_t SZ_RING2 = (size_t)2 * BH * 2;         // h2 ring depth 2
  const size_t SZ_FLG   = FLG_ARR_U16 * 2 * 2;        // flag1 + flagL1, bytes
  const size_t TOTAL = SZ_XT + SZ_WIH0 + 3 * SZ_W + 2 * SZ_B + SZ_RING1 +
                       SZ_RING2 + SZ_FLG;

  if (ws_size < TOTAL) {
    k_diag<<<1, 1, 0, stream>>>((float*)d_out, (float)(ws_size >> 20));
    return;
  }

  char* ws = (char*)d_ws;
  size_t off = 0;
  f16* xt    = (f16*)(ws + off); off += SZ_XT;
  f16* cwih0 = (f16*)(ws + off); off += SZ_WIH0;
  f16* cwhh0 = (f16*)(ws + off); off += SZ_W;
  f16* cwih1 = (f16*)(ws + off); off += SZ_W;
  f16* cwhh1 = (f16*)(ws + off); off += SZ_W;
  float* b0  = (float*)(ws + off); off += SZ_B;
  float* b1  = (float*)(ws + off); off += SZ_B;
  f16* h1r   = (f16*)(ws + off); off += SZ_RING1;
  f16* h2r   = (f16*)(ws + off); off += SZ_RING2;
  uint16_t* flag1  = (uint16_t*)(ws + off); off += FLG_ARR_U16 * 2;
  uint16_t* flagL1 = (uint16_t*)(ws + off); off += FLG_ARR_U16 * 2;

  hipMemsetAsync(flag1, 0, SZ_FLG, stream);
  k_conv_w<<<4096, 256, 0, stream>>>(wih0, whh0, wih1, whh1, bih0, bhh0, bih1, bhh1,
                                     cwih0, cwhh0, cwih1, cwhh1, b0, b1);
  k_conv_x<<<4096, 256, 0, stream>>>(x, xt);
  k_fused<<<512, 256, 0, stream>>>(xt, cwih0, cwhh0, cwih1, cwhh1, b0, b1,
                                   h1r, h2r, flag1, flagL1);
  // h2_255 is in ring slot (255&1)==1
  k_fc<<<256, 64, 0, stream>>>(h2r + BH, fcw, fcb, (float*)d_out);
}

// Round 17
// 1418.172 us; speedup vs baseline: 1.1897x; 1.1897x over previous
//
#include <hip/hip_runtime.h>
#include <stdint.h>

typedef _Float16 f16;
typedef _Float16 f16x8 __attribute__((ext_vector_type(8)));
typedef float f32x4 __attribute__((ext_vector_type(4)));

#define TT 256
#define BB 256
#define II 128
#define HH 512
#define G4 2048
#define NGRP 8
static constexpr size_t BH = (size_t)BB * HH;
// flag line: 256B per (grp,tick) = 128 u16 slots (32 slices x 4 waves)
static constexpr size_t FLG_LINE_U16 = 128;

// ---------------- coherence helpers (sc1/agent — proven protocol) ----------------
__device__ __forceinline__ uint64_t ld_agent_u64(const uint64_t* p) {
  return __hip_atomic_load(p, __ATOMIC_RELAXED, __HIP_MEMORY_SCOPE_AGENT);
}
__device__ __forceinline__ void st_agent_u64(uint64_t* p, uint64_t v) {
  __hip_atomic_store(p, v, __ATOMIC_RELAXED, __HIP_MEMORY_SCOPE_AGENT);
}
__device__ __forceinline__ void st_agent_u16(uint16_t* p, uint16_t v) {
  __hip_atomic_store(p, v, __ATOMIC_RELAXED, __HIP_MEMORY_SCOPE_AGENT);
}
// 16x dwordx4 sc1 loads: 8 granules h1 row-part, 8 granules h2 row-part
// (stride 128B). Ends with vmcnt(8): h1 quads ready; caller drains vmcnt(0)
// before touching v[8..15]. Outputs early-clobber.
__device__ __forceinline__ void ld16_sc1(const void* b1, const void* b2, uint4 v[16]) {
  asm volatile(
      "global_load_dwordx4 %0, %16, off sc1\n\t"
      "global_load_dwordx4 %1, %16, off offset:128 sc1\n\t"
      "global_load_dwordx4 %2, %16, off offset:256 sc1\n\t"
      "global_load_dwordx4 %3, %16, off offset:384 sc1\n\t"
      "global_load_dwordx4 %4, %16, off offset:512 sc1\n\t"
      "global_load_dwordx4 %5, %16, off offset:640 sc1\n\t"
      "global_load_dwordx4 %6, %16, off offset:768 sc1\n\t"
      "global_load_dwordx4 %7, %16, off offset:896 sc1\n\t"
      "global_load_dwordx4 %8, %17, off sc1\n\t"
      "global_load_dwordx4 %9, %17, off offset:128 sc1\n\t"
      "global_load_dwordx4 %10, %17, off offset:256 sc1\n\t"
      "global_load_dwordx4 %11, %17, off offset:384 sc1\n\t"
      "global_load_dwordx4 %12, %17, off offset:512 sc1\n\t"
      "global_load_dwordx4 %13, %17, off offset:640 sc1\n\t"
      "global_load_dwordx4 %14, %17, off offset:768 sc1\n\t"
      "global_load_dwordx4 %15, %17, off offset:896 sc1\n\t"
      "s_waitcnt vmcnt(8)"
      : "=&v"(v[0]), "=&v"(v[1]), "=&v"(v[2]), "=&v"(v[3]),
        "=&v"(v[4]), "=&v"(v[5]), "=&v"(v[6]), "=&v"(v[7]),
        "=&v"(v[8]), "=&v"(v[9]), "=&v"(v[10]), "=&v"(v[11]),
        "=&v"(v[12]), "=&v"(v[13]), "=&v"(v[14]), "=&v"(v[15])
      : "v"(b1), "v"(b2)
      : "memory");
}

__device__ __forceinline__ float fsig(float x) {
  x = fminf(fmaxf(x, -30.f), 30.f);
  float e = __builtin_amdgcn_exp2f(-1.44269504f * x);
  return __builtin_amdgcn_rcpf(1.f + e);
}
__device__ __forceinline__ float ftanh(float x) {
  x = fminf(fmaxf(x, -15.f), 15.f);
  float e = __builtin_amdgcn_exp2f(-2.88539008f * x);  // exp(-2x)
  return (1.f - e) * __builtin_amdgcn_rcpf(1.f + e);
}

// swizzled LDS fragment reads (granule = 16B, XOR with row&7)
__device__ __forceinline__ f16x8 ldfragh(const f16* S, int row, int gi) {
  return *(const f16x8*)(S + row * 512 + ((gi ^ (row & 7)) * 8));
}
__device__ __forceinline__ f16x8 ldfragx(const f16* S, int row, int gi) {
  return *(const f16x8*)(S + row * 128 + ((gi ^ (row & 7)) * 8));
}

__global__ void k_diag(float* out, float val) { out[0] = val; }

// ---------------- x transpose/convert: [B][T][I] f32 -> [T][B][I] f16 ----------------
__global__ __launch_bounds__(256) void k_conv_x(const float* __restrict__ x,
                                                f16* __restrict__ xt) {
  int idx = blockIdx.x * 256 + threadIdx.x;  // unit = 8 floats
  int row = idx >> 4;                        // row = t*B + b
  int ii = (idx & 15) * 8;
  int t = row >> 8, b = row & 255;
  const float4* xs = (const float4*)(x + ((size_t)b * TT + t) * II + ii);
  float4 v0 = xs[0];
  float4 v1 = xs[1];
  f16x8 h;
  h[0] = (f16)v0.x; h[1] = (f16)v0.y; h[2] = (f16)v0.z; h[3] = (f16)v0.w;
  h[4] = (f16)v1.x; h[5] = (f16)v1.y; h[6] = (f16)v1.z; h[7] = (f16)v1.w;
  *(f16x8*)(xt + (size_t)row * II + ii) = h;
}

// ---------------- convert weights to f16, sum biases ----------------
__global__ __launch_bounds__(256) void k_conv_w(
    const float* __restrict__ wih0, const float* __restrict__ whh0,
    const float* __restrict__ wih1, const float* __restrict__ whh1,
    const float* __restrict__ bih0, const float* __restrict__ bhh0,
    const float* __restrict__ bih1, const float* __restrict__ bhh1,
    f16* owih0, f16* owhh0, f16* owih1, f16* owhh1, float* ob0, float* ob1) {
  int i = blockIdx.x * 256 + threadIdx.x;
  if (i < G4 * II) owih0[i] = (f16)wih0[i];
  if (i < G4 * HH) {
    owhh0[i] = (f16)whh0[i];
    owih1[i] = (f16)wih1[i];
    owhh1[i] = (f16)whh1[i];
  }
  if (i < G4) {
    ob0[i] = bih0[i] + bhh0[i];
    ob1[i] = bih1[i] + bhh1[i];
  }
}

// ---------------- fused 2-layer wavefront LSTM (R11: session-best, final) ----------
// 256 blocks x 256 threads = 8 batch-groups (grp=bx&7, 32 rows) x 32
// col-slices (slice=bx>>3, 16 h-cols). Tick u: L0 step u (u<T), L1 step u-1.
// Handshake: sc1/MALL flags; PER-WAVE flag slots (each wave drains its own
// stores — vmcnt is wave-local — and flags immediately); 2 barriers/tick.
// Session ledger: protocol-structural changes won (fences->sc1 12x,
// RMW->flags 2x, per-wave flags 1.1x); all throughput knobs and all four
// overlap restructures (R4/R10/R14/R16) were null or negative. The tick is
// a serial chain of cross-XCD coherence RTTs with zero-slack h1 — this
// structure's floor, 18.6x faster than the first correct version.
__global__ __launch_bounds__(256, 1) void k_fused(
    const f16* __restrict__ xt,
    const f16* __restrict__ Wih0, const f16* __restrict__ Whh0,
    const f16* __restrict__ Wih1, const f16* __restrict__ Whh1,
    const float* __restrict__ b0, const float* __restrict__ b1,
    f16* __restrict__ h1r, f16* __restrict__ h2r, uint16_t* __restrict__ flags) {
  __shared__ __align__(16) f16 h1s[32 * 512];   // 32KB, swizzled
  __shared__ __align__(16) f16 h2s[32 * 512];   // 32KB, swizzled
  __shared__ __align__(16) f16 xs[32 * 128];    // 8KB, swizzled
  __shared__ __align__(16) float gs[2][64][36]; // gate preacts [layer][gcol][row+pad]

  int tid = threadIdx.x;
  int l64 = tid & 63;
  int wid = tid >> 6;        // wave = gate chunk (i,f,g,o)
  int lm = l64 & 15, ls = l64 >> 4;
  int bx = blockIdx.x;
  int grp = bx & 7;
  int slice = bx >> 3;       // 0..31
  int col0 = slice * 16;
  int row0 = grp * 32;

  // ---- preload weight fragments (plain loads; static; live in VGPR/AGPR) ----
  int wrow = wid * 512 + col0 + lm;  // gate-col = row of W
  f16x8 wih0f[4], whh0f[16], wih1f[16], whh1f[16];
#pragma unroll
  for (int kk = 0; kk < 4; ++kk)
    wih0f[kk] = *(const f16x8*)(Wih0 + (size_t)wrow * II + kk * 32 + ls * 8);
#pragma unroll
  for (int kk = 0; kk < 16; ++kk) {
    whh0f[kk] = *(const f16x8*)(Whh0 + (size_t)wrow * HH + kk * 32 + ls * 8);
    wih1f[kk] = *(const f16x8*)(Wih1 + (size_t)wrow * HH + kk * 32 + ls * 8);
    whh1f[kk] = *(const f16x8*)(Whh1 + (size_t)wrow * HH + kk * 32 + ls * 8);
  }

  // ---- elementwise role: waves 0-1 -> layer0, waves 2-3 -> layer1 ----
  int el = tid >> 7;         // layer
  int er = (tid >> 2) & 31;  // local batch row
  int eq = tid & 3;          // col quad (4 consecutive cols)
  const float* bsrc = el ? b1 : b0;
  float bias[4][4];
#pragma unroll
  for (int g = 0; g < 4; ++g)
#pragma unroll
    for (int j = 0; j < 4; ++j) bias[g][j] = bsrc[g * HH + col0 + eq * 4 + j];
  float cst[4] = {0.f, 0.f, 0.f, 0.f};
  f16* ering = el ? h2r : h1r;

  // staging role: row sr = tid>>3 (0..31), granule gx = tid&7 (16B units)
  int sr = tid >> 3;
  int gx = tid & 7;
  const uint64_t kTarget = 0x0001000100010001ULL;

#pragma unroll 1
  for (int u = 0; u <= TT; ++u) {
    // x_u -> swizzled LDS BEFORE the poll (independent of handshake; prior
    // tick's xs reads completed before barrier2(u-1), which all threads passed)
    if (u < TT) {
      const uint4* src = (const uint4*)(xt + ((size_t)u * BB + row0 + sr) * II);
      uint4 xv0 = src[gx];
      uint4 xv1 = src[gx + 8];
      uint4* dx = (uint4*)xs;
      dx[sr * 16 + (gx ^ (sr & 7))] = xv0;
      dx[sr * 16 + ((gx + 8) ^ (sr & 7))] = xv1;
    }
    if (u > 0) {
      // poll the (grp, u-1) flag line: 128 u16 slots == 1 (32 u64 words)
      const uint64_t* fl =
          (const uint64_t*)(flags + ((size_t)grp * (TT + 1) + (u - 1)) * FLG_LINE_U16);
      int guard = 0;
      for (;;) {
        uint64_t v = ld_agent_u64(fl + (l64 & 31));
        if (__all(v == kTarget)) break;
        if (++guard > 500000) break;  // deadlock safety net
        __builtin_amdgcn_s_sleep(1);
      }
      asm volatile("" ::: "memory");  // no hoisting data loads above poll
      // ---- stage h1_{u-1} (slot (u-1)&1) and h2_{u-2} (slot u&1) ----
      const f16* base1 =
          h1r + (size_t)((u - 1) & 1) * BH + (size_t)(row0 + sr) * HH + gx * 8;
      const f16* base2 =
          h2r + (size_t)(u & 1) * BH + (size_t)(row0 + sr) * HH + gx * 8;
      uint4 hv[16];
      ld16_sc1(base1, base2, hv);  // ends vmcnt(8): h1 quads ready
      uint4* d1 = (uint4*)h1s;
#pragma unroll
      for (int q = 0; q < 8; ++q) {
        int gi = gx + q * 8;
        d1[sr * 64 + (gi ^ (sr & 7))] = hv[q];
      }
      asm volatile("s_waitcnt vmcnt(0)" ::: "memory");  // h2 quads ready
      uint4* d2 = (uint4*)h2s;
#pragma unroll
      for (int q = 0; q < 8; ++q) {
        int gi = gx + q * 8;
        d2[sr * 64 + (gi ^ (sr & 7))] = hv[8 + q];
      }
    }
    __syncthreads();  // barrier1: h1s/h2s/xs visible; orders gs(u-1) reads vs gs(u) writes

    // ---- MFMA: wave wid computes gate chunk wid, 16 cols, 32 rows ----
    f32x4 a0f0 = {0.f, 0.f, 0.f, 0.f}, a0f1 = {0.f, 0.f, 0.f, 0.f};
    f32x4 a1f0 = {0.f, 0.f, 0.f, 0.f}, a1f1 = {0.f, 0.f, 0.f, 0.f};
    if (u < TT) {  // L0 x-projection, K=128
#pragma unroll
      for (int kk = 0; kk < 4; ++kk) {
        f16x8 xA = ldfragx(xs, lm, kk * 4 + ls);
        f16x8 xB = ldfragx(xs, 16 + lm, kk * 4 + ls);
        a0f0 = __builtin_amdgcn_mfma_f32_16x16x32_f16(xA, wih0f[kk], a0f0, 0, 0, 0);
        a0f1 = __builtin_amdgcn_mfma_f32_16x16x32_f16(xB, wih0f[kk], a0f1, 0, 0, 0);
      }
    }
    if (u > 0) {  // h1_{u-1} feeds L0 recurrence AND L1 input projection
#pragma unroll
      for (int kk = 0; kk < 16; ++kk) {
        f16x8 hA = ldfragh(h1s, lm, kk * 4 + ls);
        f16x8 hB = ldfragh(h1s, 16 + lm, kk * 4 + ls);
        if (u < TT) {
          a0f0 = __builtin_amdgcn_mfma_f32_16x16x32_f16(hA, whh0f[kk], a0f0, 0, 0, 0);
          a0f1 = __builtin_amdgcn_mfma_f32_16x16x32_f16(hB, whh0f[kk], a0f1, 0, 0, 0);
        }
        a1f0 = __builtin_amdgcn_mfma_f32_16x16x32_f16(hA, wih1f[kk], a1f0, 0, 0, 0);
        a1f1 = __builtin_amdgcn_mfma_f32_16x16x32_f16(hB, wih1f[kk], a1f1, 0, 0, 0);
      }
      if (u >= 2) {  // L1 recurrence over h2_{u-2}
#pragma unroll
        for (int kk = 0; kk < 16; ++kk) {
          f16x8 hA = ldfragh(h2s, lm, kk * 4 + ls);
          f16x8 hB = ldfragh(h2s, 16 + lm, kk * 4 + ls);
          a1f0 = __builtin_amdgcn_mfma_f32_16x16x32_f16(hA, whh1f[kk], a1f0, 0, 0, 0);
          a1f1 = __builtin_amdgcn_mfma_f32_16x16x32_f16(hB, whh1f[kk], a1f1, 0, 0, 0);
        }
      }
    }
    // acc -> gs[layer][gcol][row]; C layout: col=lane&15, row=(lane>>4)*4+reg
    *(f32x4*)&gs[0][wid * 16 + lm][ls * 4] = a0f0;
    *(f32x4*)&gs[0][wid * 16 + lm][16 + ls * 4] = a0f1;
    *(f32x4*)&gs[1][wid * 16 + lm][ls * 4] = a1f0;
    *(f32x4*)&gs[1][wid * 16 + lm][16 + ls * 4] = a1f1;
    __syncthreads();  // barrier2: gs visible; all LDS reads of this tick done

    // ---- elementwise LSTM cell: 4 cells/thread (layer el, row er, cols eq*4..+3)
    bool act = el ? (u >= 1) : (u < TT);
    if (act) {
      int t_l = el ? (u - 1) : u;
      int slot = t_l & 1;
      union { uint64_t v; unsigned short us[4]; } pk;
#pragma unroll
      for (int j = 0; j < 4; ++j) {
        int cl = eq * 4 + j;
        float pi = gs[el][0 * 16 + cl][er] + bias[0][j];
        float pf = gs[el][1 * 16 + cl][er] + bias[1][j];
        float pg = gs[el][2 * 16 + cl][er] + bias[2][j];
        float po = gs[el][3 * 16 + cl][er] + bias[3][j];
        float ig = fsig(pi), fg = fsig(pf), gg = ftanh(pg), og = fsig(po);
        cst[j] = fg * cst[j] + ig * gg;
        pk.us[j] = __builtin_bit_cast(unsigned short, (f16)(og * ftanh(cst[j])));
      }
      uint64_t* dst = (uint64_t*)(ering + (size_t)slot * BH +
                                  (size_t)(row0 + er) * HH + col0 + eq * 4);
      st_agent_u64(dst, pk.v);
    }
    // per-wave tail: wave-local drain, then lane0 flags THIS wave's slot.
    if (u < TT) {
      asm volatile("s_waitcnt vmcnt(0)" ::: "memory");  // this wave's stores at MALL
      if (l64 == 0)
        st_agent_u16(flags + ((size_t)grp * (TT + 1) + u) * FLG_LINE_U16 +
                         slice * 4 + wid,
                     1u);
    }
  }
}

// ---------------- FC head: out[b] = h2_last[b][:] . fcw + fcb ----------------
__global__ __launch_bounds__(64) void k_fc(const f16* __restrict__ h2,
                                           const float* __restrict__ fcw,
                                           const float* __restrict__ fcb,
                                           float* __restrict__ out) {
  int b = blockIdx.x;
  int l = threadIdx.x;
  f16x8 hv = *(const f16x8*)(h2 + (size_t)b * HH + l * 8);
  float4 w0 = ((const float4*)fcw)[l * 2];
  float4 w1 = ((const float4*)fcw)[l * 2 + 1];
  float s = (float)hv[0] * w0.x + (float)hv[1] * w0.y + (float)hv[2] * w0.z +
            (float)hv[3] * w0.w + (float)hv[4] * w1.x + (float)hv[5] * w1.y +
            (float)hv[6] * w1.z + (float)hv[7] * w1.w;
#pragma unroll
  for (int off = 32; off > 0; off >>= 1) s += __shfl_down(s, off);
  if (l == 0) out[b] = s + fcb[0];
}

// ---------------- launch ----------------
extern "C" void kernel_launch(void* const* d_in, const int* in_sizes, int n_in,
                              void* d_out, int out_size, void* d_ws, size_t ws_size,
                              hipStream_t stream) {
  (void)in_sizes; (void)n_in; (void)out_size;

  const float* x    = (const float*)d_in[0];
  const float* wih0 = (const float*)d_in[1];
  const float* whh0 = (const float*)d_in[2];
  const float* bih0 = (const float*)d_in[3];
  const float* bhh0 = (const float*)d_in[4];
  const float* wih1 = (const float*)d_in[5];
  const float* whh1 = (const float*)d_in[6];
  const float* bih1 = (const float*)d_in[7];
  const float* bhh1 = (const float*)d_in[8];
  const float* fcw  = (const float*)d_in[9];
  const float* fcb  = (const float*)d_in[10];

  const size_t SZ_XT   = (size_t)TT * BB * II * 2;              // 16.8 MB
  const size_t SZ_WIH0 = (size_t)G4 * II * 2;
  const size_t SZ_W    = (size_t)G4 * HH * 2;
  const size_t SZ_B    = (size_t)G4 * 4;
  const size_t SZ_RING = (size_t)2 * BH * 2;
  const size_t SZ_FLG  = (size_t)NGRP * (TT + 1) * FLG_LINE_U16 * 2;  // 256B/line
  const size_t TOTAL =
      SZ_XT + SZ_WIH0 + 3 * SZ_W + 2 * SZ_B + 2 * SZ_RING + SZ_FLG;

  if (ws_size < TOTAL) {
    k_diag<<<1, 1, 0, stream>>>((float*)d_out, (float)(ws_size >> 20));
    return;
  }

  char* ws = (char*)d_ws;
  size_t off = 0;
  f16* xt    = (f16*)(ws + off); off += SZ_XT;
  f16* cwih0 = (f16*)(ws + off); off += SZ_WIH0;
  f16* cwhh0 = (f16*)(ws + off); off += SZ_W;
  f16* cwih1 = (f16*)(ws + off); off += SZ_W;
  f16* cwhh1 = (f16*)(ws + off); off += SZ_W;
  float* b0  = (float*)(ws + off); off += SZ_B;
  float* b1  = (float*)(ws + off); off += SZ_B;
  f16* h1r   = (f16*)(ws + off); off += SZ_RING;
  f16* h2r   = (f16*)(ws + off); off += SZ_RING;
  uint16_t* flags = (uint16_t*)(ws + off); off += SZ_FLG;

  hipMemsetAsync(flags, 0, SZ_FLG, stream);
  k_conv_w<<<4096, 256, 0, stream>>>(wih0, whh0, wih1, whh1, bih0, bhh0, bih1, bhh1,
                                     cwih0, cwhh0, cwih1, cwhh1, b0, b1);
  k_conv_x<<<4096, 256, 0, stream>>>(x, xt);
  k_fused<<<256, 256, 0, stream>>>(xt, cwih0, cwhh0, cwih1, cwhh1, b0, b1,
                                   h1r, h2r, flags);
  // h2_255 is in ring slot (255&1)==1
  k_fc<<<256, 64, 0, stream>>>(h2r + BH, fcw, fcb, (float*)d_out);
}